// Round 1
// baseline (489.326 us; speedup 1.0000x reference)
//
#include <hip/hip_runtime.h>

typedef __bf16 bf16;
typedef __bf16 bf16x8 __attribute__((ext_vector_type(8)));
typedef float  f32x4  __attribute__((ext_vector_type(4)));

#define MFMA16(a, b, c) __builtin_amdgcn_mfma_f32_16x16x32_bf16((a), (b), (c), 0, 0, 0)

// async global->LDS, 16 B per lane: lane l -> ldsbase + l*16 (wave-uniform base).
__device__ inline void gl_lds16(const bf16* g, bf16* l) {
  __builtin_amdgcn_global_load_lds(
      (const __attribute__((address_space(1))) void*)g,
      (__attribute__((address_space(3))) void*)l, 16, 0, 0);
}

__device__ inline bf16x8 cvt8(const float* __restrict__ f) {
  float4 a = *(const float4*)f;
  float4 b = *(const float4*)(f + 4);
  bf16x8 r;
  r[0] = (bf16)a.x; r[1] = (bf16)a.y; r[2] = (bf16)a.z; r[3] = (bf16)a.w;
  r[4] = (bf16)b.x; r[5] = (bf16)b.y; r[6] = (bf16)b.z; r[7] = (bf16)b.w;
  return r;
}

// ---------------------------------------------------------------------------
__global__ void cvt_f32_bf16(const float* __restrict__ src, bf16* __restrict__ dst,
                             int n8) {
  int i = blockIdx.x * 256 + threadIdx.x;
  if (i >= n8) return;
  *(bf16x8*)(dst + (size_t)i * 8) = cvt8(src + (size_t)i * 8);
}

// ---------------------------------------------------------------------------
// GEMM: C[M,N] = A[M,K] @ W[N,K]^T, bf16 MFMA, fp32 accum.
// 128x128 tile, BK=64, 4 waves (2x2), 4x4 16x16x32 MFMA per wave.
// LDS in MFMA-FRAGMENT ORDER: 16 frags x 1KB per operand. Frag (mi,s):
// lane l holds A[m0+mi*16+(l&15)][k0+s*32+(l>>4)*8 ..+7]. Staged via
// global_load_lds (per-lane global gather, lane-contiguous LDS) -> fragment
// reads are `frag_base + lane*16`: ZERO bank conflicts (fix for r5's 16-way).
// AF32: A staged in same fragment order via VGPR cvt8 (fp32 source).
// Split output: blocks with n0 >= Nsplit use A1/C1 (fused K+V projection).
// ---------------------------------------------------------------------------
template <bool AF32, bool OUTF32>
__global__ __launch_bounds__(256) void gemm_bt(const void* __restrict__ Ap0,
                                               const void* __restrict__ Ap1,
                                               const bf16* __restrict__ W,
                                               void* __restrict__ C0,
                                               void* __restrict__ C1,
                                               int Nsplit, int ld0, int ld1,
                                               int M, int N, int K) {
  __shared__ alignas(16) bf16 As[16 * 512];   // 16 KB, fragment-ordered
  __shared__ alignas(16) bf16 Bs[16 * 512];

  const int tid  = threadIdx.x;
  const int wave = tid >> 6, lane = tid & 63;
  const int wm = wave >> 1, wn = wave & 1;
  const int lr = lane & 15, quad = lane >> 4;
  const int m0 = blockIdx.y * 128, n0 = blockIdx.x * 128;

  const bool second = (n0 >= Nsplit);
  const void* Ap = second ? Ap1 : Ap0;

  f32x4 vzero = {0.f, 0.f, 0.f, 0.f};
  f32x4 acc[4][4];
#pragma unroll
  for (int mt = 0; mt < 4; ++mt)
#pragma unroll
    for (int nt = 0; nt < 4; ++nt) acc[mt][nt] = vzero;

  for (int k0 = 0; k0 < K; k0 += 64) {
    // ---- stage B frags (wave w: chunks 4w..4w+3) ----
#pragma unroll
    for (int j = 0; j < 4; ++j) {
      int c = wave * 4 + j;               // frag id: mi = c>>1, s = c&1
      gl_lds16(W + (size_t)(n0 + (c >> 1) * 16 + lr) * K + k0 + (c & 1) * 32 + quad * 8,
               Bs + c * 512);
    }
    // ---- stage A frags ----
    if (AF32) {
#pragma unroll
      for (int j = 0; j < 4; ++j) {
        int c = wave * 4 + j;
        *(bf16x8*)(As + c * 512 + lane * 8) =
            cvt8((const float*)Ap + (size_t)(m0 + (c >> 1) * 16 + lr) * K +
                 k0 + (c & 1) * 32 + quad * 8);
      }
    } else {
#pragma unroll
      for (int j = 0; j < 4; ++j) {
        int c = wave * 4 + j;
        gl_lds16((const bf16*)Ap + (size_t)(m0 + (c >> 1) * 16 + lr) * K +
                     k0 + (c & 1) * 32 + quad * 8,
                 As + c * 512);
      }
    }
    __syncthreads();

#pragma unroll
    for (int s = 0; s < 2; ++s) {
      bf16x8 af[4], bfg[4];
#pragma unroll
      for (int mt = 0; mt < 4; ++mt)
        af[mt] = *(const bf16x8*)(As + ((wm * 4 + mt) * 2 + s) * 512 + lane * 8);
#pragma unroll
      for (int nt = 0; nt < 4; ++nt)
        bfg[nt] = *(const bf16x8*)(Bs + ((wn * 4 + nt) * 2 + s) * 512 + lane * 8);
#pragma unroll
      for (int mt = 0; mt < 4; ++mt)
#pragma unroll
        for (int nt = 0; nt < 4; ++nt)
          acc[mt][nt] = MFMA16(af[mt], bfg[nt], acc[mt][nt]);
    }
    __syncthreads();
  }

  // epilogue: C/D layout col = lane&15, row = quad*4 + e   [HW-verified m89]
  void* Cb = second ? C1 : C0;
  const int ld = second ? ld1 : ld0;
  const int nb = second ? n0 - Nsplit : n0;
#pragma unroll
  for (int mt = 0; mt < 4; ++mt) {
    int row = m0 + wm * 64 + mt * 16 + quad * 4;
#pragma unroll
    for (int nt = 0; nt < 4; ++nt) {
      int col = nb + wn * 64 + nt * 16 + lr;
#pragma unroll
      for (int e = 0; e < 4; ++e) {
        if (OUTF32)
          ((float*)Cb)[(size_t)(row + e) * ld + col] = acc[mt][nt][e];
        else
          ((bf16*)Cb)[(size_t)(row + e) * ld + col] = (bf16)acc[mt][nt][e];
      }
    }
  }
}

// ---------------------------------------------------------------------------
// RoPE + clip (+scale fold), in place, vectorized: 8 (j,j+64) pairs/thread.
// ---------------------------------------------------------------------------
__global__ void rope_clip(bf16* __restrict__ X, int heads, float scl) {
  int tpr = heads * 8;
  int idx = blockIdx.x * 256 + threadIdx.x;
  if (idx >= 4096 * tpr) return;
  int r = idx / tpr;
  int rem = idx - r * tpr;
  int h = rem >> 3, j0 = (rem & 7) * 8;
  int l = r & 2047;
  size_t base = (size_t)r * (heads * 128) + h * 128 + j0;
  bf16x8 x1 = *(const bf16x8*)(X + base);
  bf16x8 x2 = *(const bf16x8*)(X + base + 64);
  bf16x8 y1, y2;
#pragma unroll
  for (int t = 0; t < 8; ++t) {
    int j = j0 + t;
    float inv = expf(-(float)j * (9.210340371976184f / 64.0f));
    float s, c;
    sincosf((float)l * inv, &s, &c);
    float a = (float)x1[t], b = (float)x2[t];
    float u = a * c - b * s;
    float v = a * s + b * c;
    y1[t] = (bf16)(fminf(fmaxf(u, -50.f), 50.f) * scl);
    y2[t] = (bf16)(fminf(fmaxf(v, -50.f), 50.f) * scl);
  }
  *(bf16x8*)(X + base)      = y1;
  *(bf16x8*)(X + base + 64) = y2;
}

// ---------------------------------------------------------------------------
// Transpose per batch: in (R x Cc) -> out (Cc x R).
// ---------------------------------------------------------------------------
__global__ void transpose_bf16(const bf16* __restrict__ in, bf16* __restrict__ out,
                               int R, int Cc) {
  __shared__ bf16 t[32][33];
  int b = blockIdx.z;
  const bf16* ip = in + (size_t)b * R * Cc;
  bf16* op = out + (size_t)b * R * Cc;
  int c0 = blockIdx.x * 32, r0 = blockIdx.y * 32;
  int lx = threadIdx.x, ly = threadIdx.y;
#pragma unroll
  for (int i = 0; i < 32; i += 8)
    t[ly + i][lx] = ip[(size_t)(r0 + ly + i) * Cc + c0 + lx];
  __syncthreads();
#pragma unroll
  for (int i = 0; i < 32; i += 8)
    op[(size_t)(c0 + ly + i) * R + r0 + lx] = t[lx][ly + i];
}

// ---------------------------------------------------------------------------
// Flash v5, causal, GQA (16 qh -> 4 kvh), DK=128, L=2048.
// 256 thr = 4 waves; 128 q-rows/block, **32 q-rows/wave** (two 16-row
// m-tiles). Halves K/V LDS read traffic per FLOP vs v4 (each kf/vf
// fragment read feeds 2 MFMAs) and halves barrier population — v4's
// counters showed LDS-pipe bound (MfmaUtil 13.7%, all pipes <20%).
// K/V staged FRAGMENT-ORDERED via global_load_lds: K frags (kt,ks) 16x1KB,
// V frags (dt,ks2) 16x1KB -> conflict-free lane*16 reads.
// P keeps the stride-72 padded LDS round-trip (per-wave private, no barrier).
// Fixed-max softmax (v2-verified). Balanced causal swizzle.
// ---------------------------------------------------------------------------
__global__ __launch_bounds__(256, 2) void flash(const bf16* __restrict__ Q,
                                                const bf16* __restrict__ Kp,
                                                const bf16* __restrict__ Vt,
                                                bf16* __restrict__ Ctx) {
  __shared__ alignas(16) bf16 Ks[16 * 512];   // 16 KB
  __shared__ alignas(16) bf16 Vs[16 * 512];   // 16 KB
  __shared__ alignas(16) bf16 Ps[4 * 32 * 72];  // 18 KB

  const int tid  = threadIdx.x;
  const int wave = tid >> 6, lane = tid & 63;
  const int lr = lane & 15, quad = lane >> 4;
  const int bh = blockIdx.y;
  const int b = bh >> 4, h = bh & 15, hk = h >> 2;
  const int ix = blockIdx.x;
  const int qt = (ix & 1) ? (15 - (ix >> 1)) : (ix >> 1);  // balance causal work
  const int q0 = qt * 128;
  const int qb = q0 + wave * 32;            // this wave's 32 q-rows

  // Q fragments for the wave's two 16-row m-tiles
  bf16x8 qf[2][4];
#pragma unroll
  for (int mt = 0; mt < 2; ++mt) {
    const bf16* qptr =
        Q + ((size_t)(b * 2048 + qb + mt * 16 + lr)) * 2048 + h * 128 + quad * 8;
#pragma unroll
    for (int ks = 0; ks < 4; ++ks) qf[mt][ks] = *(const bf16x8*)(qptr + ks * 32);
  }

  f32x4 vzero = {0.f, 0.f, 0.f, 0.f};
  f32x4 o[2][8];
#pragma unroll
  for (int mt = 0; mt < 2; ++mt)
#pragma unroll
    for (int dt = 0; dt < 8; ++dt) o[mt][dt] = vzero;
  float fls[2][4] = {{0.f, 0.f, 0.f, 0.f}, {0.f, 0.f, 0.f, 0.f}};

  const bf16* kbase = Kp + (size_t)(b * 2048) * 512 + hk * 128;
  const bf16* vbase = Vt + ((size_t)(b * 512 + hk * 128)) * 2048;

  const int kmax = q0 + 128;
  for (int k0 = 0; k0 < kmax; k0 += 64) {
    // stage 32 frag-chunks (16 K + 16 V), 8 per wave, fragment-ordered
#pragma unroll
    for (int j = 0; j < 8; ++j) {
      int c = wave * 8 + j;
      if (c < 16) {  // K frag: kt = c>>2, ks = c&3
        gl_lds16(kbase + (size_t)(k0 + (c >> 2) * 16 + lr) * 512 + (c & 3) * 32 + quad * 8,
                 Ks + c * 512);
      } else {       // V frag: dt = (c-16)>>1, ks2 = (c-16)&1
        int c2 = c - 16;
        gl_lds16(vbase + (size_t)((c2 >> 1) * 16 + lr) * 2048 + k0 + (c2 & 1) * 32 + quad * 8,
                 Vs + c2 * 512);
      }
    }
    __syncthreads();

    if (k0 <= qb + 31) {  // wave-uniform causal skip
      f32x4 s[2][4];
#pragma unroll
      for (int mt = 0; mt < 2; ++mt)
#pragma unroll
        for (int kt = 0; kt < 4; ++kt) s[mt][kt] = vzero;
#pragma unroll
      for (int ks = 0; ks < 4; ++ks) {
#pragma unroll
        for (int kt = 0; kt < 4; ++kt) {
          bf16x8 kf = *(const bf16x8*)(Ks + (kt * 4 + ks) * 512 + lane * 8);
          s[0][kt] = MFMA16(qf[0][ks], kf, s[0][kt]);
          s[1][kt] = MFMA16(qf[1][ks], kf, s[1][kt]);
        }
      }
      bf16* pw = Ps + wave * (32 * 72);
#pragma unroll
      for (int mt = 0; mt < 2; ++mt) {
#pragma unroll
        for (int kt = 0; kt < 4; ++kt) {
          int kid = k0 + kt * 16 + lr;
#pragma unroll
          for (int e = 0; e < 4; ++e) {
            int qi = qb + mt * 16 + quad * 4 + e;
            float p = (kid <= qi) ? __expf(s[mt][kt][e]) : 0.f;
            fls[mt][e] += p;
            pw[(mt * 16 + quad * 4 + e) * 72 + kt * 16 + lr] = (bf16)p;
          }
        }
      }
#pragma unroll
      for (int ks2 = 0; ks2 < 2; ++ks2) {
        bf16x8 pf0 = *(const bf16x8*)(pw + (size_t)lr * 72 + ks2 * 32 + quad * 8);
        bf16x8 pf1 = *(const bf16x8*)(pw + (size_t)(16 + lr) * 72 + ks2 * 32 + quad * 8);
#pragma unroll
        for (int dt = 0; dt < 8; ++dt) {
          bf16x8 vf = *(const bf16x8*)(Vs + (dt * 2 + ks2) * 512 + lane * 8);
          o[0][dt] = MFMA16(pf0, vf, o[0][dt]);
          o[1][dt] = MFMA16(pf1, vf, o[1][dt]);
        }
      }
    }
    __syncthreads();
  }

  // one-time denominator reduce across the 16 key-lanes
#pragma unroll
  for (int mt = 0; mt < 2; ++mt) {
#pragma unroll
    for (int e = 0; e < 4; ++e) {
      float s = fls[mt][e];
      s += __shfl_xor(s, 1);
      s += __shfl_xor(s, 2);
      s += __shfl_xor(s, 4);
      s += __shfl_xor(s, 8);
      fls[mt][e] = 1.0f / s;
    }
  }

#pragma unroll
  for (int mt = 0; mt < 2; ++mt) {
    bf16* cptr =
        Ctx + ((size_t)(b * 2048 + qb + mt * 16 + quad * 4)) * 2048 + h * 128 + lr;
#pragma unroll
    for (int dt = 0; dt < 8; ++dt)
#pragma unroll
      for (int e = 0; e < 4; ++e)
        cptr[(size_t)e * 2048 + dt * 16] = (bf16)(o[mt][dt][e] * fls[mt][e]);
  }
}

// ---------------------------------------------------------------------------
extern "C" void kernel_launch(void* const* d_in, const int* in_sizes, int n_in,
                              void* d_out, int out_size, void* d_ws, size_t ws_size,
                              hipStream_t stream) {
  (void)in_sizes; (void)n_in; (void)out_size; (void)ws_size;
  const float* query = (const float*)d_in[0];
  const float* key_t = (const float*)d_in[1];
  const float* value = (const float*)d_in[2];
  // d_in[3] = mask (causal tril) — applied analytically
  const float* Wq = (const float*)d_in[4];
  const float* Wk = (const float*)d_in[5];
  const float* Wv = (const float*)d_in[6];
  const float* Wo = (const float*)d_in[7];

  const size_t MB = 1024ull * 1024ull;
  char* ws  = (char*)d_ws;
  bf16* qbf = (bf16*)(ws);                  // [0,16)  query bf16
  bf16* wqb = (bf16*)(ws + 16 * MB);        // [16,24)
  bf16* wkb = (bf16*)(ws + 24 * MB);        // [24,26)  Wk bf16
  bf16* wvb = (bf16*)(ws + 26 * MB);        // [26,28)  Wv bf16 (contiguous with Wk)
  bf16* wob = (bf16*)(ws + 28 * MB);        // [28,36)
  bf16* Qb  = (bf16*)(ws + 36 * MB);        // [36,52)
  bf16* Kb  = (bf16*)(ws + 52 * MB);        // [52,56)
  bf16* Vb  = (bf16*)(ws + 56 * MB);        // [56,60)
  bf16* Vtb = (bf16*)(ws + 60 * MB);        // [60,64)
  bf16* Ctx = qbf;                          // alias: qbf dead after Q-proj

  cvt_f32_bf16<<<4096, 256, 0, stream>>>(query, qbf, 1048576);
  cvt_f32_bf16<<<2048, 256, 0, stream>>>(Wq, wqb, 524288);
  cvt_f32_bf16<<<512, 256, 0, stream>>>(Wk, wkb, 131072);
  cvt_f32_bf16<<<512, 256, 0, stream>>>(Wv, wvb, 131072);
  cvt_f32_bf16<<<2048, 256, 0, stream>>>(Wo, wob, 524288);

  // Q-projection: pure-bf16, both operands via fragment-ordered global_load_lds
  gemm_bt<false, false><<<dim3(16, 32), 256, 0, stream>>>(
      qbf, qbf, wqb, Qb, Qb, 2048, 2048, 2048, 4096, 2048, 2048);

  // fused K+V projection: N=1024 (Wk||Wv), A = key_t / value per half, fp32 A
  gemm_bt<true, false><<<dim3(8, 32), 256, 0, stream>>>(
      key_t, value, wkb, Kb, Vb, 512, 512, 512, 4096, 1024, 2048);

  rope_clip<<<2048, 256, 0, stream>>>(Qb, 16, 0.08838834764831845f);
  rope_clip<<<512, 256, 0, stream>>>(Kb, 4, 1.0f);

  transpose_bf16<<<dim3(16, 64, 2), dim3(32, 8), 0, stream>>>(Vb, Vtb, 2048, 512);

  flash<<<dim3(16, 32), 256, 0, stream>>>(Qb, Kb, Vtb, Ctx);

  // O-projection: bf16 A (Ctx), fp32 output
  gemm_bt<false, true><<<dim3(16, 32), 256, 0, stream>>>(
      Ctx, Ctx, wob, (float*)d_out, (float*)d_out, 2048, 2048, 2048, 4096, 2048, 2048);
}

// Round 3
// 460.331 us; speedup vs baseline: 1.0630x; 1.0630x over previous
//
#include <hip/hip_runtime.h>

typedef __bf16 bf16;
typedef __bf16 bf16x8 __attribute__((ext_vector_type(8)));
typedef float  f32x4  __attribute__((ext_vector_type(4)));

#define MFMA16(a, b, c) __builtin_amdgcn_mfma_f32_16x16x32_bf16((a), (b), (c), 0, 0, 0)

// async global->LDS, 16 B per lane: lane l -> ldsbase + l*16 (wave-uniform base).
__device__ inline void gl_lds16(const bf16* g, bf16* l) {
  __builtin_amdgcn_global_load_lds(
      (const __attribute__((address_space(1))) void*)g,
      (__attribute__((address_space(3))) void*)l, 16, 0, 0);
}

__device__ inline bf16x8 cvt8(const float* __restrict__ f) {
  float4 a = *(const float4*)f;
  float4 b = *(const float4*)(f + 4);
  bf16x8 r;
  r[0] = (bf16)a.x; r[1] = (bf16)a.y; r[2] = (bf16)a.z; r[3] = (bf16)a.w;
  r[4] = (bf16)b.x; r[5] = (bf16)b.y; r[6] = (bf16)b.z; r[7] = (bf16)b.w;
  return r;
}

// ---------------------------------------------------------------------------
__global__ void cvt_f32_bf16(const float* __restrict__ src, bf16* __restrict__ dst,
                             int n8) {
  int i = blockIdx.x * 256 + threadIdx.x;
  if (i >= n8) return;
  *(bf16x8*)(dst + (size_t)i * 8) = cvt8(src + (size_t)i * 8);
}

// ---------------------------------------------------------------------------
// GEMM: C[M,N] = A[M,K] @ W[N,K]^T, bf16 MFMA, fp32 accum.
// 128x128 tile, BK=64, 4 waves (2x2), 4x4 16x16x32 MFMA per wave.
// LDS in MFMA-FRAGMENT ORDER: 16 frags x 1KB per operand. Staged via
// global_load_lds -> fragment reads are `frag_base + lane*16`: conflict-free.
// AF32: A staged in same fragment order via VGPR cvt8 (fp32 source).
// Split output: blocks with n0 >= Nsplit use A1/C1 (fused K+V projection).
// ---------------------------------------------------------------------------
template <bool AF32, bool OUTF32>
__global__ __launch_bounds__(256) void gemm_bt(const void* __restrict__ Ap0,
                                               const void* __restrict__ Ap1,
                                               const bf16* __restrict__ W,
                                               void* __restrict__ C0,
                                               void* __restrict__ C1,
                                               int Nsplit, int ld0, int ld1,
                                               int M, int N, int K) {
  __shared__ alignas(16) bf16 As[16 * 512];   // 16 KB, fragment-ordered
  __shared__ alignas(16) bf16 Bs[16 * 512];

  const int tid  = threadIdx.x;
  const int wave = tid >> 6, lane = tid & 63;
  const int wm = wave >> 1, wn = wave & 1;
  const int lr = lane & 15, quad = lane >> 4;
  const int m0 = blockIdx.y * 128, n0 = blockIdx.x * 128;

  const bool second = (n0 >= Nsplit);
  const void* Ap = second ? Ap1 : Ap0;

  f32x4 vzero = {0.f, 0.f, 0.f, 0.f};
  f32x4 acc[4][4];
#pragma unroll
  for (int mt = 0; mt < 4; ++mt)
#pragma unroll
    for (int nt = 0; nt < 4; ++nt) acc[mt][nt] = vzero;

  for (int k0 = 0; k0 < K; k0 += 64) {
    // ---- stage B frags (wave w: chunks 4w..4w+3) ----
#pragma unroll
    for (int j = 0; j < 4; ++j) {
      int c = wave * 4 + j;               // frag id: mi = c>>1, s = c&1
      gl_lds16(W + (size_t)(n0 + (c >> 1) * 16 + lr) * K + k0 + (c & 1) * 32 + quad * 8,
               Bs + c * 512);
    }
    // ---- stage A frags ----
    if (AF32) {
#pragma unroll
      for (int j = 0; j < 4; ++j) {
        int c = wave * 4 + j;
        *(bf16x8*)(As + c * 512 + lane * 8) =
            cvt8((const float*)Ap + (size_t)(m0 + (c >> 1) * 16 + lr) * K +
                 k0 + (c & 1) * 32 + quad * 8);
      }
    } else {
#pragma unroll
      for (int j = 0; j < 4; ++j) {
        int c = wave * 4 + j;
        gl_lds16((const bf16*)Ap + (size_t)(m0 + (c >> 1) * 16 + lr) * K +
                     k0 + (c & 1) * 32 + quad * 8,
                 As + c * 512);
      }
    }
    __syncthreads();

#pragma unroll
    for (int s = 0; s < 2; ++s) {
      bf16x8 af[4], bfg[4];
#pragma unroll
      for (int mt = 0; mt < 4; ++mt)
        af[mt] = *(const bf16x8*)(As + ((wm * 4 + mt) * 2 + s) * 512 + lane * 8);
#pragma unroll
      for (int nt = 0; nt < 4; ++nt)
        bfg[nt] = *(const bf16x8*)(Bs + ((wn * 4 + nt) * 2 + s) * 512 + lane * 8);
#pragma unroll
      for (int mt = 0; mt < 4; ++mt)
#pragma unroll
        for (int nt = 0; nt < 4; ++nt)
          acc[mt][nt] = MFMA16(af[mt], bfg[nt], acc[mt][nt]);
    }
    __syncthreads();
  }

  // epilogue: C/D layout col = lane&15, row = quad*4 + e   [HW-verified m89]
  void* Cb = second ? C1 : C0;
  const int ld = second ? ld1 : ld0;
  const int nb = second ? n0 - Nsplit : n0;
#pragma unroll
  for (int mt = 0; mt < 4; ++mt) {
    int row = m0 + wm * 64 + mt * 16 + quad * 4;
#pragma unroll
    for (int nt = 0; nt < 4; ++nt) {
      int col = nb + wn * 64 + nt * 16 + lr;
#pragma unroll
      for (int e = 0; e < 4; ++e) {
        if (OUTF32)
          ((float*)Cb)[(size_t)(row + e) * ld + col] = acc[mt][nt][e];
        else
          ((bf16*)Cb)[(size_t)(row + e) * ld + col] = (bf16)acc[mt][nt][e];
      }
    }
  }
}

// ---------------------------------------------------------------------------
// RoPE + clip (+scale fold), in place, vectorized: 8 (j,j+64) pairs/thread.
// ---------------------------------------------------------------------------
__global__ void rope_clip(bf16* __restrict__ X, int heads, float scl) {
  int tpr = heads * 8;
  int idx = blockIdx.x * 256 + threadIdx.x;
  if (idx >= 4096 * tpr) return;
  int r = idx / tpr;
  int rem = idx - r * tpr;
  int h = rem >> 3, j0 = (rem & 7) * 8;
  int l = r & 2047;
  size_t base = (size_t)r * (heads * 128) + h * 128 + j0;
  bf16x8 x1 = *(const bf16x8*)(X + base);
  bf16x8 x2 = *(const bf16x8*)(X + base + 64);
  bf16x8 y1, y2;
#pragma unroll
  for (int t = 0; t < 8; ++t) {
    int j = j0 + t;
    float inv = expf(-(float)j * (9.210340371976184f / 64.0f));
    float s, c;
    sincosf((float)l * inv, &s, &c);
    float a = (float)x1[t], b = (float)x2[t];
    float u = a * c - b * s;
    float v = a * s + b * c;
    y1[t] = (bf16)(fminf(fmaxf(u, -50.f), 50.f) * scl);
    y2[t] = (bf16)(fminf(fmaxf(v, -50.f), 50.f) * scl);
  }
  *(bf16x8*)(X + base)      = y1;
  *(bf16x8*)(X + base + 64) = y2;
}

// ---------------------------------------------------------------------------
// Transpose per batch: in (R x Cc) -> out (Cc x R).
// ---------------------------------------------------------------------------
__global__ void transpose_bf16(const bf16* __restrict__ in, bf16* __restrict__ out,
                               int R, int Cc) {
  __shared__ bf16 t[32][33];
  int b = blockIdx.z;
  const bf16* ip = in + (size_t)b * R * Cc;
  bf16* op = out + (size_t)b * R * Cc;
  int c0 = blockIdx.x * 32, r0 = blockIdx.y * 32;
  int lx = threadIdx.x, ly = threadIdx.y;
#pragma unroll
  for (int i = 0; i < 32; i += 8)
    t[ly + i][lx] = ip[(size_t)(r0 + ly + i) * Cc + c0 + lx];
  __syncthreads();
#pragma unroll
  for (int i = 0; i < 32; i += 8)
    op[(size_t)(c0 + ly + i) * R + r0 + lx] = t[lx][ly + i];
}

// ---------------------------------------------------------------------------
// Flash v6, causal, GQA (16 qh -> 4 kvh), DK=128, L=2048.
// UNIFORM-WORK PAIRED BLOCKS + 2-PHASE COUNTED-vmcnt PIPELINE.
// Each block owns the q-tile pair (qt=p, qt=15-p): 8 waves, each wave has
// 16 rows of tile A and 16 rows of tile B. One k-loop to kmaxB; tile A
// rides along while active, sharing the staged K/V chunk AND the kf/vf
// fragment reads. Every block does 32-34 wave-tile-computes -> 256 blocks
// of UNIFORM work = exactly 1/CU, balanced regardless of dispatch order.
// (v4/v5 put both same-qt blocks on one CU -> ~1.9x makespan inflation.)
// K/V double-buffered (2x32KB); STAGE(next) issued BEFORE compute with
// s_waitcnt vmcnt(4) (counted: drains only previous chunk's 4 loads/wave)
// + raw s_barrier -> stage latency hides under compute instead of the
// per-iteration vmcnt(0) drain __syncthreads forced.
// LDS: 64KB K/V dbuf + 36KB P (32 rows/wave, stride 72) = 100KB, 1 blk/CU.
// ---------------------------------------------------------------------------
__global__ __launch_bounds__(512, 2) void flash(const bf16* __restrict__ Q,
                                                const bf16* __restrict__ Kp,
                                                const bf16* __restrict__ Vt,
                                                bf16* __restrict__ Ctx) {
  __shared__ alignas(16) bf16 Ks[2][16 * 512];   // 2 x 16 KB
  __shared__ alignas(16) bf16 Vs[2][16 * 512];   // 2 x 16 KB
  __shared__ alignas(16) bf16 Ps[8][32 * 72];    // 36 KB

  const int tid  = threadIdx.x;
  const int wave = tid >> 6, lane = tid & 63;
  const int lr = lane & 15, quad = lane >> 4;
  const int bh = blockIdx.y;
  const int b = bh >> 4, h = bh & 15, hk = h >> 2;
  const int p = blockIdx.x;                     // 0..7 -> pair (p, 15-p)
  const int qA0 = p * 128, qB0 = (15 - p) * 128;
  const int qbA = qA0 + wave * 16;              // wave's rows in tile A
  const int qbB = qB0 + wave * 16;              // wave's rows in tile B
  const int nt = (qB0 + 128) >> 6;              // 32 - 2p chunk iterations

  // Q fragments for both tiles
  bf16x8 qfA[4], qfB[4];
  {
    const bf16* qa = Q + ((size_t)(b * 2048 + qbA + lr)) * 2048 + h * 128 + quad * 8;
    const bf16* qbp = Q + ((size_t)(b * 2048 + qbB + lr)) * 2048 + h * 128 + quad * 8;
#pragma unroll
    for (int ks = 0; ks < 4; ++ks) {
      qfA[ks] = *(const bf16x8*)(qa + ks * 32);
      qfB[ks] = *(const bf16x8*)(qbp + ks * 32);
    }
  }

  f32x4 vzero = {0.f, 0.f, 0.f, 0.f};
  f32x4 oA[8], oB[8];
#pragma unroll
  for (int dt = 0; dt < 8; ++dt) { oA[dt] = vzero; oB[dt] = vzero; }
  float flsA[4] = {0.f, 0.f, 0.f, 0.f};
  float flsB[4] = {0.f, 0.f, 0.f, 0.f};

  const bf16* kbase = Kp + (size_t)(b * 2048) * 512 + hk * 128;
  const bf16* vbase = Vt + ((size_t)(b * 512 + hk * 128)) * 2048;

  // stage 32 frag-chunks (16 K + 16 V), 4 per wave, fragment-ordered
#define STAGE(bufi, kk)                                                         \
  do {                                                                          \
    _Pragma("unroll") for (int j = 0; j < 4; ++j) {                             \
      int c = wave * 4 + j;                                                     \
      if (c < 16) {                                                             \
        gl_lds16(kbase + (size_t)((kk) + (c >> 2) * 16 + lr) * 512 +            \
                     (c & 3) * 32 + quad * 8,                                   \
                 &Ks[bufi][c * 512]);                                           \
      } else {                                                                  \
        int c2 = c - 16;                                                        \
        gl_lds16(vbase + (size_t)((c2 >> 1) * 16 + lr) * 2048 + (kk) +          \
                     (c2 & 1) * 32 + quad * 8,                                  \
                 &Vs[bufi][c2 * 512]);                                          \
      }                                                                         \
    }                                                                           \
  } while (0)

  STAGE(0, 0);  // prologue: chunk 0 -> buf 0
  int cur = 0;

  for (int t = 0; t < nt; ++t) {
    const int k0 = t * 64;
    if (t + 1 < nt) {
      STAGE(cur ^ 1, k0 + 64);  // issue next chunk before compute
      asm volatile("s_waitcnt vmcnt(4)" ::: "memory");  // wait prev chunk only
    } else {
      asm volatile("s_waitcnt vmcnt(0)" ::: "memory");
    }
    __builtin_amdgcn_s_barrier();   // all waves: chunk t fully staged

    const bf16* ksb = Ks[cur];
    const bf16* vsb = Vs[cur];

    if (k0 <= qbA + 15) {
      // ---- dual: tile A active => tile B active (and B never masked here) --
      f32x4 sA[4], sB[4];
#pragma unroll
      for (int kt = 0; kt < 4; ++kt) { sA[kt] = vzero; sB[kt] = vzero; }
#pragma unroll
      for (int ks = 0; ks < 4; ++ks) {
#pragma unroll
        for (int kt = 0; kt < 4; ++kt) {
          bf16x8 kf = *(const bf16x8*)(ksb + (kt * 4 + ks) * 512 + lane * 8);
          sA[kt] = MFMA16(qfA[ks], kf, sA[kt]);
          sB[kt] = MFMA16(qfB[ks], kf, sB[kt]);
        }
      }
      bf16* pwA = Ps[wave];
      bf16* pwB = Ps[wave] + 16 * 72;
#pragma unroll
      for (int kt = 0; kt < 4; ++kt) {
        int kid = k0 + kt * 16 + lr;
#pragma unroll
        for (int e = 0; e < 4; ++e) {
          int qr = quad * 4 + e;
          float pa = (kid <= qbA + qr) ? __expf(sA[kt][e]) : 0.f;
          float pb = __expf(sB[kt][e]);  // kid < 1024 <= qbB always
          flsA[e] += pa;
          flsB[e] += pb;
          pwA[qr * 72 + kt * 16 + lr] = (bf16)pa;
          pwB[qr * 72 + kt * 16 + lr] = (bf16)pb;
        }
      }
#pragma unroll
      for (int ks2 = 0; ks2 < 2; ++ks2) {
        bf16x8 pfA = *(const bf16x8*)(pwA + (size_t)lr * 72 + ks2 * 32 + quad * 8);
        bf16x8 pfB = *(const bf16x8*)(pwB + (size_t)lr * 72 + ks2 * 32 + quad * 8);
#pragma unroll
        for (int dt = 0; dt < 8; ++dt) {
          bf16x8 vf = *(const bf16x8*)(vsb + (dt * 2 + ks2) * 512 + lane * 8);
          oA[dt] = MFMA16(pfA, vf, oA[dt]);
          oB[dt] = MFMA16(pfB, vf, oB[dt]);
        }
      }
    } else if (k0 <= qbB + 15) {
      // ---- tile B only ----
      f32x4 s[4];
#pragma unroll
      for (int kt = 0; kt < 4; ++kt) s[kt] = vzero;
#pragma unroll
      for (int ks = 0; ks < 4; ++ks) {
#pragma unroll
        for (int kt = 0; kt < 4; ++kt) {
          bf16x8 kf = *(const bf16x8*)(ksb + (kt * 4 + ks) * 512 + lane * 8);
          s[kt] = MFMA16(qfB[ks], kf, s[kt]);
        }
      }
      bf16* pwB = Ps[wave] + 16 * 72;
#pragma unroll
      for (int kt = 0; kt < 4; ++kt) {
        int kid = k0 + kt * 16 + lr;
#pragma unroll
        for (int e = 0; e < 4; ++e) {
          int qr = quad * 4 + e;
          float pb = (kid <= qbB + qr) ? __expf(s[kt][e]) : 0.f;
          flsB[e] += pb;
          pwB[qr * 72 + kt * 16 + lr] = (bf16)pb;
        }
      }
#pragma unroll
      for (int ks2 = 0; ks2 < 2; ++ks2) {
        bf16x8 pf = *(const bf16x8*)(pwB + (size_t)lr * 72 + ks2 * 32 + quad * 8);
#pragma unroll
        for (int dt = 0; dt < 8; ++dt) {
          bf16x8 vf = *(const bf16x8*)(vsb + (dt * 2 + ks2) * 512 + lane * 8);
          oB[dt] = MFMA16(pf, vf, oB[dt]);
        }
      }
    }
    __builtin_amdgcn_s_barrier();   // all reads of buf[cur] done -> reusable
    cur ^= 1;
  }
#undef STAGE

  // denominator reduce across the 16 key-lanes
#pragma unroll
  for (int e = 0; e < 4; ++e) {
    float sa = flsA[e];
    sa += __shfl_xor(sa, 1);
    sa += __shfl_xor(sa, 2);
    sa += __shfl_xor(sa, 4);
    sa += __shfl_xor(sa, 8);
    flsA[e] = 1.0f / sa;
    float sb = flsB[e];
    sb += __shfl_xor(sb, 1);
    sb += __shfl_xor(sb, 2);
    sb += __shfl_xor(sb, 4);
    sb += __shfl_xor(sb, 8);
    flsB[e] = 1.0f / sb;
  }

  bf16* ca = Ctx + ((size_t)(b * 2048 + qbA + quad * 4)) * 2048 + h * 128 + lr;
  bf16* cb = Ctx + ((size_t)(b * 2048 + qbB + quad * 4)) * 2048 + h * 128 + lr;
#pragma unroll
  for (int dt = 0; dt < 8; ++dt)
#pragma unroll
    for (int e = 0; e < 4; ++e) {
      ca[(size_t)e * 2048 + dt * 16] = (bf16)(oA[dt][e] * flsA[e]);
      cb[(size_t)e * 2048 + dt * 16] = (bf16)(oB[dt][e] * flsB[e]);
    }
}

// ---------------------------------------------------------------------------
extern "C" void kernel_launch(void* const* d_in, const int* in_sizes, int n_in,
                              void* d_out, int out_size, void* d_ws, size_t ws_size,
                              hipStream_t stream) {
  (void)in_sizes; (void)n_in; (void)out_size; (void)ws_size;
  const float* query = (const float*)d_in[0];
  const float* key_t = (const float*)d_in[1];
  const float* value = (const float*)d_in[2];
  // d_in[3] = mask (causal tril) — applied analytically
  const float* Wq = (const float*)d_in[4];
  const float* Wk = (const float*)d_in[5];
  const float* Wv = (const float*)d_in[6];
  const float* Wo = (const float*)d_in[7];

  const size_t MB = 1024ull * 1024ull;
  char* ws  = (char*)d_ws;
  bf16* qbf = (bf16*)(ws);                  // [0,16)  query bf16
  bf16* wqb = (bf16*)(ws + 16 * MB);        // [16,24)
  bf16* wkb = (bf16*)(ws + 24 * MB);        // [24,26)  Wk bf16
  bf16* wvb = (bf16*)(ws + 26 * MB);        // [26,28)  Wv bf16 (contiguous with Wk)
  bf16* wob = (bf16*)(ws + 28 * MB);        // [28,36)
  bf16* Qb  = (bf16*)(ws + 36 * MB);        // [36,52)
  bf16* Kb  = (bf16*)(ws + 52 * MB);        // [52,56)
  bf16* Vb  = (bf16*)(ws + 56 * MB);        // [56,60)
  bf16* Vtb = (bf16*)(ws + 60 * MB);        // [60,64)
  bf16* Ctx = qbf;                          // alias: qbf dead after Q-proj

  cvt_f32_bf16<<<4096, 256, 0, stream>>>(query, qbf, 1048576);
  cvt_f32_bf16<<<2048, 256, 0, stream>>>(Wq, wqb, 524288);
  cvt_f32_bf16<<<512, 256, 0, stream>>>(Wk, wkb, 131072);
  cvt_f32_bf16<<<512, 256, 0, stream>>>(Wv, wvb, 131072);
  cvt_f32_bf16<<<2048, 256, 0, stream>>>(Wo, wob, 524288);

  // Q-projection: pure-bf16, both operands via fragment-ordered global_load_lds
  gemm_bt<false, false><<<dim3(16, 32), 256, 0, stream>>>(
      qbf, qbf, wqb, Qb, Qb, 2048, 2048, 2048, 4096, 2048, 2048);

  // fused K+V projection: N=1024 (Wk||Wv), A = key_t / value per half, fp32 A
  gemm_bt<true, false><<<dim3(8, 32), 256, 0, stream>>>(
      key_t, value, wkb, Kb, Vb, 512, 512, 512, 4096, 1024, 2048);

  rope_clip<<<2048, 256, 0, stream>>>(Qb, 16, 0.08838834764831845f);
  rope_clip<<<512, 256, 0, stream>>>(Kb, 4, 1.0f);

  transpose_bf16<<<dim3(16, 64, 2), dim3(32, 8), 0, stream>>>(Vb, Vtb, 2048, 512);

  flash<<<dim3(8, 32), 512, 0, stream>>>(Qb, Kb, Vtb, Ctx);

  // O-projection: bf16 A (Ctx), fp32 output
  gemm_bt<false, true><<<dim3(16, 32), 256, 0, stream>>>(
      Ctx, Ctx, wob, (float*)d_out, (float*)d_out, 2048, 2048, 2048, 4096, 2048, 2048);
}